// Round 10
// baseline (153.280 us; speedup 1.0000x reference)
//
#include <hip/hip_runtime.h>
#include <hip/hip_cooperative_groups.h>
#include <math.h>

namespace cg = cooperative_groups;

#define NC 32
#define NSTEPS 32
#define NB 8192            // composed-map intervals per theta (2^13)

constexpr int MT     = 512;
constexpr int MPTS   = 8;
constexpr int MCHUNK = MT * MPTS;          // 4096 points per block

// ---------------------------------------------------------------------------
// Chain table for theta j into LDS:
//   tb[c]      = A_c  = e^a
//   tb[32 + c] = Bz_c = 32 * b * phi(a)    (z-domain offset, exact 2^5)
// Arithmetic identical to rounds 0-9 (absmax canary depends on it).
// Caller must __syncthreads() after.
// ---------------------------------------------------------------------------
__device__ inline void compute_tab(float* tb, const float* __restrict__ theta,
                                   const float* __restrict__ basis,
                                   int j, int d, int tid) {
    if (tid < NC) {
        const int c = tid;
        const float* __restrict__ th = theta + j * d;
        const float* __restrict__ ba = basis + (2 * c) * d;
        const float* __restrict__ bb = basis + (2 * c + 1) * d;
        float a = 0.0f, b = 0.0f;
#pragma unroll 6
        for (int k = 0; k < d; ++k) {
            float t = th[k];
            a = fmaf(ba[k], t, a);
            b = fmaf(bb[k], t, b);
        }
        const float dT = 1.0f / (float)NSTEPS;
        a *= dT;
        b *= dT;
        float A = expf(a);
        // phi(a) = (e^a - 1)/a, stable small-a branch (matches reference)
        float phi = (fabsf(a) < 1e-6f) ? (1.0f + 0.5f * a) : (expm1f(a) / a);
        tb[c]      = A;
        tb[c + NC] = 32.0f * (b * phi);
    }
}

// ---------------------------------------------------------------------------
// Single cooperative kernel.
// Phase A (first n_theta*NB threads = 128 blocks): compose the 32-step map
//   on NB dyadic intervals per theta. Interval i covers x in
//   [i*2^-13,(i+1)*2^-13) -> z = 32x in [i*2^-8, pred((i+1)*2^-8)]. Both
//   endpoints run the EXACT fp32 z-domain recurrence; each step map is
//   monotone in z (A>0, RN monotone) and cell = clip(floor) is monotone, so
//   if cell(zlo)==cell(zhi) at every step ("pure") every fp32 point in the
//   interval follows the same cell sequence. Pure: composed affine (S,T)
//   accumulated in fp64, flagged impure via -S.  [identical math to R9]
// grid.sync()
// Phase B (all 512 blocks, one theta per block): per point ONE global 8B
//   gather from the L2-resident ST table + fma. Impure points -> LDS list ->
//   bit-exact 32-step chain replay (LDS tab, SoA, broadcast-merge free).
// ---------------------------------------------------------------------------
__global__ void __launch_bounds__(MT, 4)
cpab_coop(const float* __restrict__ points,
          const float* __restrict__ theta,
          const float* __restrict__ basis,
          float2* __restrict__ ST,
          float* __restrict__ out,
          int n_points, int d, int n_theta) {
    __shared__ float tb[2 * NC];
    __shared__ unsigned short ll[MCHUNK];      // impure offsets (8 KB)
    __shared__ unsigned lcnt;

    const int tid = threadIdx.x;

    // ---------------- Phase A: compose ----------------
    const int total_chains = n_theta * NB;     // 65536
    const int q0 = blockIdx.x * MT;
    if (q0 < total_chains) {
        const int jA = q0 >> 13;               // NB=8192 chains per theta
        compute_tab(tb, theta, basis, jA, d, tid);
        __syncthreads();

        const int i = (q0 + tid) & (NB - 1);
        float zlo = (float)i * 0.00390625f;                       // i*2^-8
        float zhi = __uint_as_float(
            __float_as_uint((float)(i + 1) * 0.00390625f) - 1u);  // pred
        double Sd = 1.0, Td = 0.0;
        bool pure = true;
#pragma unroll
        for (int s = 0; s < NSTEPS; ++s) {
            float flo = fminf(fmaxf(zlo, 0.0f), 31.5f);
            float fhi = fminf(fmaxf(zhi, 0.0f), 31.5f);
            int clo = (int)flo, chi = (int)fhi;
            pure = pure && (clo == chi);
            float Al = tb[clo], Bl = tb[NC + clo];
            float Ah = tb[chi], Bh = tb[NC + chi];
            Sd *= (double)Al;
            Td = fma((double)Al, Td, (double)Bl);
            zlo = fmaf(Al, zlo, Bl);
            zhi = fmaf(Ah, zhi, Bh);
        }
        float S = (float)Sd;
        // out(x) = fmaf(S, x, T/32); /32 exact
        ST[jA * NB + i] = make_float2(pure ? S : -S,
                                      (float)(Td * (1.0 / 32.0)));
        __threadfence();                       // device-scope release
    }

    cg::this_grid().sync();                    // compose visible grid-wide

    // ---------------- Phase B: apply ----------------
    const int bpt = n_points / MCHUNK;         // 64 blocks per theta
    const int j = blockIdx.x / bpt;
    const int cbase = (blockIdx.x % bpt) * MCHUNK;

    compute_tab(tb, theta, basis, j, d, tid);  // this block's theta
    if (tid == 0) lcnt = 0;
    __syncthreads();

    const float2* __restrict__ stj = ST + j * NB;

#pragma unroll
    for (int i = 0; i < MPTS; ++i) {
        int off = i * MT + tid;
        float x = points[cbase + off];         // coalesced
        float f = fminf(fmaxf(x * 8192.0f, 0.0f), 8191.5f); // exact 2^13
        float2 t = stj[(int)f];                // L2-resident random 8B load
        if (t.x > 0.0f) {
            out[j * n_points + cbase + off] = fmaf(t.x, x, t.y);
        } else {
            unsigned s = atomicAdd(&lcnt, 1u);
            ll[s] = (unsigned short)off;
        }
    }
    __syncthreads();

    // impure replay: bit-exact 32-step chain (~12% of points)
    unsigned n = lcnt;
    for (unsigned k = tid; k < n; k += MT) {
        int off = ll[k];
        float z = points[cbase + off] * 32.0f; // exact 2^5 scale
#pragma unroll
        for (int s = 0; s < NSTEPS; ++s) {
            float zc = fminf(fmaxf(z, 0.0f), 31.5f);
            int c = (int)zc;
            z = fmaf(tb[c], z, tb[NC + c]);
        }
        out[j * n_points + cbase + off] = z * 0.03125f; // exact scale back
    }
}

extern "C" void kernel_launch(void* const* d_in, const int* in_sizes, int n_in,
                              void* d_out, int out_size, void* d_ws, size_t ws_size,
                              hipStream_t stream) {
    const float* points = (const float*)d_in[0];  // [1, n_points]
    const float* theta  = (const float*)d_in[1];  // [n_theta, d]
    const float* basis  = (const float*)d_in[2];  // [2*NC, d]

    int n_points = in_sizes[0];
    int d        = in_sizes[2] / (2 * NC);        // 30
    int n_theta  = in_sizes[1] / d;               // 8

    float2* ST = (float2*)d_ws;                   // 512 KB composed table
    float*  out = (float*)d_out;

    int grid = n_theta * (n_points / MCHUNK);     // 512 blocks (2/CU)

    void* args[] = {(void*)&points, (void*)&theta, (void*)&basis,
                    (void*)&ST, (void*)&out,
                    (void*)&n_points, (void*)&d, (void*)&n_theta};
    hipLaunchCooperativeKernel((void*)cpab_coop, dim3(grid), dim3(MT),
                               args, 0, stream);
}

// Round 11
// 76.700 us; speedup vs baseline: 1.9984x; 1.9984x over previous
//
#include <hip/hip_runtime.h>
#include <math.h>

#define NC 32
#define NSTEPS 32
#define NB 8192            // composed-map intervals per theta (2^13)

// ---------------------------------------------------------------------------
// Chain table for theta j into LDS:
//   tb[c]      = A_c  = e^a
//   tb[32 + c] = Bz_c = 32 * b * phi(a)    (z-domain offset, exact 2^5)
// Arithmetic identical to rounds 0-10 (absmax canary depends on it).
// Caller must __syncthreads() after.
// ---------------------------------------------------------------------------
__device__ inline void compute_tab(float* tb, const float* __restrict__ theta,
                                   const float* __restrict__ basis,
                                   int j, int d, int tid) {
    if (tid < NC) {
        const int c = tid;
        const float* __restrict__ th = theta + j * d;
        const float* __restrict__ ba = basis + (2 * c) * d;
        const float* __restrict__ bb = basis + (2 * c + 1) * d;
        float a = 0.0f, b = 0.0f;
#pragma unroll 6
        for (int k = 0; k < d; ++k) {
            float t = th[k];
            a = fmaf(ba[k], t, a);
            b = fmaf(bb[k], t, b);
        }
        const float dT = 1.0f / (float)NSTEPS;
        a *= dT;
        b *= dT;
        float A = expf(a);
        // phi(a) = (e^a - 1)/a, stable small-a branch (matches reference)
        float phi = (fabsf(a) < 1e-6f) ? (1.0f + 0.5f * a) : (expm1f(a) / a);
        tb[c]      = A;
        tb[c + NC] = 32.0f * (b * phi);
    }
}

// ---------------------------------------------------------------------------
// K1: compose the 32-step map on NB dyadic intervals per theta (verbatim
// R9 math — canary-exact). Interval i covers x in [i*2^-13,(i+1)*2^-13) ->
// z = 32x in [i*2^-8, pred((i+1)*2^-8)]. Both endpoints run the EXACT fp32
// z-domain recurrence; each step map is monotone in z (A>0, RN monotone) and
// cell = clip(floor) monotone, so if cell(zlo)==cell(zhi) at every step
// ("pure") every fp32 point in the interval follows the same cell sequence.
// Pure: composed affine (S,T) accumulated in fp64; impure flagged via -S
// (S = prod of e^a > 0 strictly, so sign is a safe flag).
// ---------------------------------------------------------------------------
__global__ void __launch_bounds__(256)
compose_kernel(const float* __restrict__ theta,
               const float* __restrict__ basis,
               float2* __restrict__ ST, int d) {
    __shared__ float tb[2 * NC];
    const int j  = blockIdx.x >> 5;          // 32 blocks per theta
    const int i0 = (blockIdx.x & 31) * 256;

    compute_tab(tb, theta, basis, j, d, threadIdx.x);
    __syncthreads();

    const int i = i0 + threadIdx.x;
    float zlo = (float)i * 0.00390625f;                       // i*2^-8 exact
    float zhi = __uint_as_float(
        __float_as_uint((float)(i + 1) * 0.00390625f) - 1u);  // pred, exact
    double Sd = 1.0, Td = 0.0;
    bool pure = true;
#pragma unroll
    for (int s = 0; s < NSTEPS; ++s) {
        float flo = fminf(fmaxf(zlo, 0.0f), 31.5f);
        float fhi = fminf(fmaxf(zhi, 0.0f), 31.5f);
        int clo = (int)flo, chi = (int)fhi;
        pure = pure && (clo == chi);
        float Al = tb[clo], Bl = tb[NC + clo];
        float Ah = tb[chi], Bh = tb[NC + chi];
        Sd *= (double)Al;
        Td = fma((double)Al, Td, (double)Bl);
        zlo = fmaf(Al, zlo, Bl);
        zhi = fmaf(Ah, zhi, Bh);
    }
    float S = (float)Sd;
    // out(x) = fmaf(S, x, T/32); /32 exact
    ST[j * NB + i] = make_float2(pure ? S : -S, (float)(Td * (1.0 / 32.0)));
}

// ---------------------------------------------------------------------------
// K2: apply. 256 threads, 8 pts/thread (contiguous), 1024 blocks, LDS only
// ~4.4 KB -> full occupancy, no staging barrier. (S,T) gathered DIRECTLY
// from the L2-resident global table (512 KB total, ~64 KB per theta).
// Phase 1 stores all 8 results vectorized — impure slots hold garbage that
// phase 2 (same block, after __syncthreads) overwrites with the bit-exact
// 32-step chain.
// ---------------------------------------------------------------------------
constexpr int MT     = 256;
constexpr int MPTS   = 8;
constexpr int MCHUNK = MT * MPTS;          // 2048 points per block

__global__ void __launch_bounds__(MT)
apply_kernel(const float* __restrict__ points,
             const float* __restrict__ theta,
             const float* __restrict__ basis,
             const float2* __restrict__ ST,
             float* __restrict__ out,
             int n_points, int d) {
    __shared__ float tb[2 * NC];               // 256 B chain table
    __shared__ unsigned short ll[MCHUNK];      // 4 KB impure list
    __shared__ unsigned lcnt;

    const int bpt = n_points / MCHUNK;         // 128 blocks per theta
    const int j = blockIdx.x / bpt;
    const int cbase = (blockIdx.x % bpt) * MCHUNK;
    const int tid = threadIdx.x;

    compute_tab(tb, theta, basis, j, d, tid);
    if (tid == 0) lcnt = 0;
    __syncthreads();

    const float2* __restrict__ stj = ST + j * NB;
    const int p0 = cbase + tid * MPTS;         // contiguous 8 per thread

    float x[MPTS];
    {
        float4 v0 = *(const float4*)(points + p0);
        float4 v1 = *(const float4*)(points + p0 + 4);
        x[0] = v0.x; x[1] = v0.y; x[2] = v0.z; x[3] = v0.w;
        x[4] = v1.x; x[5] = v1.y; x[6] = v1.z; x[7] = v1.w;
    }

    float r[MPTS];
#pragma unroll
    for (int i = 0; i < MPTS; ++i) {
        float f = fminf(fmaxf(x[i] * 8192.0f, 0.0f), 8191.5f); // exact 2^13
        float2 t = stj[(int)f];                // random 8B load, L2-resident
        r[i] = fmaf(t.x, x[i], t.y);           // garbage if impure (t.x<0)
        if (!(t.x > 0.0f)) {
            unsigned s = atomicAdd(&lcnt, 1u);
            ll[s] = (unsigned short)(tid * MPTS + i);
        }
    }
    {   // vectorized store; impure slots overwritten in phase 2
        float* op = out + j * n_points + p0;
        *(float4*)op       = make_float4(r[0], r[1], r[2], r[3]);
        *(float4*)(op + 4) = make_float4(r[4], r[5], r[6], r[7]);
    }
    __syncthreads();

    // Phase 2: impure points — bit-exact 32-step chain (dense waves).
    unsigned n = lcnt;
    for (unsigned k = tid; k < n; k += MT) {
        int off = ll[k];
        float z = points[cbase + off] * 32.0f; // exact 2^5 scale
#pragma unroll
        for (int s = 0; s < NSTEPS; ++s) {
            float zc = fminf(fmaxf(z, 0.0f), 31.5f);
            int c = (int)zc;
            z = fmaf(tb[c], z, tb[NC + c]);
        }
        out[j * n_points + cbase + off] = z * 0.03125f; // exact scale back
    }
}

extern "C" void kernel_launch(void* const* d_in, const int* in_sizes, int n_in,
                              void* d_out, int out_size, void* d_ws, size_t ws_size,
                              hipStream_t stream) {
    const float* points = (const float*)d_in[0];  // [1, n_points]
    const float* theta  = (const float*)d_in[1];  // [n_theta, d]
    const float* basis  = (const float*)d_in[2];  // [2*NC, d]

    int n_points = in_sizes[0];
    int d        = in_sizes[2] / (2 * NC);        // 30
    int n_theta  = in_sizes[1] / d;               // 8

    float2* ST = (float2*)d_ws;                   // 512 KB composed table

    compose_kernel<<<n_theta * (NB / 256), 256, 0, stream>>>(
        theta, basis, ST, d);
    apply_kernel<<<n_theta * (n_points / MCHUNK), MT, 0, stream>>>(
        points, theta, basis, ST, (float*)d_out, n_points, d);
}